// Round 1
// baseline (959.095 us; speedup 1.0000x reference)
//
#include <hip/hip_runtime.h>
#include <cstdint>
#include <cstddef>

#define DIM 4096
#define SEQ 2048
#define NH 32
#define NKV 8
#define HD 128
#define QKVN 6144

typedef __bf16 bf16_t;
typedef __bf16 bf16x8 __attribute__((ext_vector_type(8)));
typedef __bf16 bf16x4 __attribute__((ext_vector_type(4)));
typedef float f32x4 __attribute__((ext_vector_type(4)));

__device__ __forceinline__ f32x4 mfma16(bf16x8 a, bf16x8 b, f32x4 c) {
  return __builtin_amdgcn_mfma_f32_16x16x32_bf16(a, b, c, 0, 0, 0);
}

__device__ __forceinline__ void async16(const bf16_t* g, bf16_t* l) {
  __builtin_amdgcn_global_load_lds((__attribute__((address_space(1))) void*)g,
                                   (__attribute__((address_space(3))) void*)l,
                                   16, 0, 0);
}

// ---------------- cast x (fp32 -> bf16), 4 elems/thread ----------------
__global__ void cast_x(const float* __restrict__ x, bf16_t* __restrict__ xb) {
  int i = blockIdx.x * 256 + threadIdx.x;
  const float4 v = ((const float4*)x)[i];
  bf16x4 o = { (bf16_t)v.x, (bf16_t)v.y, (bf16_t)v.z, (bf16_t)v.w };
  *(bf16x4*)(xb + (size_t)i * 4) = o;
}

// ------- transpose-cast: src fp32 (Kdim x Ncols) -> dst bf16 (Ncols x Kdim) -------
__global__ void tcast(const float* __restrict__ src, bf16_t* __restrict__ dst,
                      int Ncols, int Kdim) {
  __shared__ float tile[32][33];
  int n0 = blockIdx.x * 32, k0 = blockIdx.y * 32;
  int tx = threadIdx.x, ty = threadIdx.y;  // 32 x 8
#pragma unroll
  for (int r = 0; r < 4; r++)
    tile[ty + 8 * r][tx] = src[(size_t)(k0 + ty + 8 * r) * Ncols + n0 + tx];
  __syncthreads();
#pragma unroll
  for (int r = 0; r < 4; r++)
    dst[(size_t)(n0 + ty + 8 * r) * Kdim + k0 + tx] = (bf16_t)tile[tx][ty + 8 * r];
}

// ---------------- GEMM: C(MxN) fp32 = A(MxK) bf16 @ Bt(NxK)^T ----------------
// m97-style: 128x128 tile, BK=32, 256 threads (4 waves, each 64x64), async LDS staging.
__global__ __launch_bounds__(256) void gemm_bt(const bf16_t* __restrict__ A,
                                               const bf16_t* __restrict__ Bt,
                                               float* __restrict__ C,
                                               int M, int N, int K) {
  __shared__ bf16_t As[128 * 32];
  __shared__ bf16_t Bs[128 * 32];
  const int t = threadIdx.x;
  const int bm = blockIdx.y * 128, bn = blockIdx.x * 128;
  const int lane = t & 63, l15 = lane & 15, quad = lane >> 4;
  const int w = t >> 6;
  const int wm = (w & 1) * 64, wn = (w >> 1) * 64;
  f32x4 acc[4][4] = {};
  const bf16_t* gA = A + (size_t)(bm + (t >> 2)) * K + (t & 3) * 8;
  const bf16_t* gB = Bt + (size_t)(bn + (t >> 2)) * K + (t & 3) * 8;
  bf16_t* lA = As + t * 8;
  bf16_t* lB = Bs + t * 8;
  for (int k0 = 0; k0 < K; k0 += 32) {
    async16(gA + k0, lA);
    async16(gA + k0 + (size_t)64 * K, lA + 2048);
    async16(gB + k0, lB);
    async16(gB + k0 + (size_t)64 * K, lB + 2048);
    __syncthreads();
    bf16x8 af[4], bfr[4];
#pragma unroll
    for (int mi = 0; mi < 4; mi++)
      af[mi] = *(const bf16x8*)(As + (wm + mi * 16 + l15) * 32 + quad * 8);
#pragma unroll
    for (int ni = 0; ni < 4; ni++)
      bfr[ni] = *(const bf16x8*)(Bs + (wn + ni * 16 + l15) * 32 + quad * 8);
#pragma unroll
    for (int mi = 0; mi < 4; mi++)
#pragma unroll
      for (int ni = 0; ni < 4; ni++)
        acc[mi][ni] = mfma16(af[mi], bfr[ni], acc[mi][ni]);
    __syncthreads();
  }
#pragma unroll
  for (int mi = 0; mi < 4; mi++)
#pragma unroll
    for (int ni = 0; ni < 4; ni++) {
      size_t row = (size_t)bm + wm + mi * 16 + quad * 4;
      size_t col = (size_t)bn + wn + ni * 16 + l15;
#pragma unroll
      for (int r = 0; r < 4; r++)
        C[(row + r) * N + col] = acc[mi][ni][r];
    }
}

// ---------------- RoPE + scatter ----------------
// qkv fp32 (2048 x 6144): [Q(4096) | K(1024) | V(1024)] per row.
// Writes: Qb bf16 (32,2048,128) roped; Kb bf16 (8,2048,128) roped;
//         Vt bf16 (8,128,2048) (V transposed); kOut/vOut fp32 (32,2048,128) repeated.
__global__ void rope_scatter(const float* __restrict__ qkv, bf16_t* __restrict__ Qb,
                             bf16_t* __restrict__ Kb, bf16_t* __restrict__ Vt,
                             float* __restrict__ kOut, float* __restrict__ vOut) {
  int idx = blockIdx.x * 256 + threadIdx.x;
  int t = idx / 3072;
  int p = idx - t * 3072;
  const float NEG_L2T_64 = -0.20762050593046f;  // -log2(10000)/64
  if (p < 2048) {  // Q: head h = p>>6, pair pr = p&63
    int hh = p >> 6, pr = p & 63;
    int d0 = pr << 1;
    const float* src = qkv + (size_t)t * QKVN + hh * HD + d0;
    float a = src[0], b = src[1];
    int j0 = d0 & 63, j1 = (d0 + 1) & 63;
    float th0 = (float)t * exp2f((float)j0 * NEG_L2T_64);
    float th1 = (float)t * exp2f((float)j1 * NEG_L2T_64);
    float o0 = a * cosf(th0) - b * sinf(th0);
    float o1 = b * cosf(th1) + a * sinf(th1);
    bf16_t* dst = Qb + ((size_t)hh * SEQ + t) * HD + d0;
    dst[0] = (bf16_t)o0;
    dst[1] = (bf16_t)o1;
  } else if (p < 2560) {  // K
    int q2 = p - 2048;
    int kh = q2 >> 6, pr = q2 & 63;
    int d0 = pr << 1;
    const float* src = qkv + (size_t)t * QKVN + 4096 + kh * HD + d0;
    float a = src[0], b = src[1];
    int j0 = d0 & 63, j1 = (d0 + 1) & 63;
    float th0 = (float)t * exp2f((float)j0 * NEG_L2T_64);
    float th1 = (float)t * exp2f((float)j1 * NEG_L2T_64);
    float o0 = a * cosf(th0) - b * sinf(th0);
    float o1 = b * cosf(th1) + a * sinf(th1);
    bf16_t* dst = Kb + ((size_t)kh * SEQ + t) * HD + d0;
    dst[0] = (bf16_t)o0;
    dst[1] = (bf16_t)o1;
#pragma unroll
    for (int rep = 0; rep < 4; rep++) {
      float* kp = kOut + ((size_t)(kh * 4 + rep) * SEQ + t) * HD + d0;
      kp[0] = o0;
      kp[1] = o1;
    }
  } else {  // V
    int q2 = p - 2560;
    int kh = q2 >> 6, pr = q2 & 63;
    int d0 = pr << 1;
    const float* src = qkv + (size_t)t * QKVN + 5120 + kh * HD + d0;
    float a = src[0], b = src[1];
#pragma unroll
    for (int rep = 0; rep < 4; rep++) {
      float* vp = vOut + ((size_t)(kh * 4 + rep) * SEQ + t) * HD + d0;
      vp[0] = a;
      vp[1] = b;
    }
    Vt[((size_t)kh * HD + d0) * SEQ + t] = (bf16_t)a;
    Vt[((size_t)kh * HD + d0 + 1) * SEQ + t] = (bf16_t)b;
  }
}

// ---------------- Flash attention ----------------
// Grid: (32 q-tiles of 64 rows, 32 heads). 256 threads = 4 waves x 16 q-rows.
// Online softmax; KT=32 keys/iter; P round-trips LDS (C-layout -> A-layout).
__global__ __launch_bounds__(256) void attn_kernel(const bf16_t* __restrict__ Qb,
                                                   const bf16_t* __restrict__ Kb,
                                                   const bf16_t* __restrict__ Vt,
                                                   bf16_t* __restrict__ AO) {
  const int h = blockIdx.y;
  const int kh = h >> 2;  // GQA: 4 Q heads per KV head
  const int qbase = blockIdx.x * 64;
  const int w = threadIdx.x >> 6, lane = threadIdx.x & 63;
  const int l15 = lane & 15, quad = lane >> 4;
  __shared__ bf16_t Plds[4][16 * 40];  // per-wave 16x32 P tile, row stride 40
  bf16_t* myP = &Plds[w][0];

  bf16x8 qf[4];
  const bf16_t* qptr = Qb + ((size_t)h * SEQ + qbase + w * 16 + l15) * HD + quad * 8;
#pragma unroll
  for (int kc = 0; kc < 4; kc++) qf[kc] = *(const bf16x8*)(qptr + kc * 32);

  f32x4 acc[8] = {};
  float mrow[4] = {-3.0e38f, -3.0e38f, -3.0e38f, -3.0e38f};
  float lrow[4] = {0.f, 0.f, 0.f, 0.f};
  const float sscale = 0.08838834764831845f * 1.4426950408889634f;  // SCALE*log2(e)

  const bf16_t* KbH = Kb + (size_t)kh * SEQ * HD;
  const bf16_t* VtH = Vt + (size_t)kh * HD * SEQ;

  for (int kt0 = 0; kt0 < SEQ; kt0 += 32) {
    f32x4 s0 = {0.f, 0.f, 0.f, 0.f}, s1 = {0.f, 0.f, 0.f, 0.f};
    const bf16_t* kp0 = KbH + (size_t)(kt0 + l15) * HD + quad * 8;
    const bf16_t* kp1 = kp0 + 16 * HD;
#pragma unroll
    for (int kc = 0; kc < 4; kc++) {
      bf16x8 b0 = *(const bf16x8*)(kp0 + kc * 32);
      bf16x8 b1 = *(const bf16x8*)(kp1 + kc * 32);
      s0 = mfma16(qf[kc], b0, s0);
      s1 = mfma16(qf[kc], b1, s1);
    }
    float mx[4], al[4], p0[4], p1[4], rs[4];
#pragma unroll
    for (int r = 0; r < 4; r++) {
      s0[r] *= sscale;
      s1[r] *= sscale;
      mx[r] = fmaxf(s0[r], s1[r]);
    }
#pragma unroll
    for (int mask = 1; mask <= 8; mask <<= 1)
#pragma unroll
      for (int r = 0; r < 4; r++)
        mx[r] = fmaxf(mx[r], __shfl_xor(mx[r], mask));
#pragma unroll
    for (int r = 0; r < 4; r++) {
      float mn = fmaxf(mrow[r], mx[r]);
      al[r] = exp2f(mrow[r] - mn);
      mrow[r] = mn;
      p0[r] = exp2f(s0[r] - mn);
      p1[r] = exp2f(s1[r] - mn);
      rs[r] = p0[r] + p1[r];
    }
#pragma unroll
    for (int mask = 1; mask <= 8; mask <<= 1)
#pragma unroll
      for (int r = 0; r < 4; r++) rs[r] += __shfl_xor(rs[r], mask);
#pragma unroll
    for (int r = 0; r < 4; r++) lrow[r] = lrow[r] * al[r] + rs[r];
#pragma unroll
    for (int dt = 0; dt < 8; dt++)
#pragma unroll
      for (int r = 0; r < 4; r++) acc[dt][r] *= al[r];
    // P: C-layout (row=quad*4+r, col=l15) -> LDS
#pragma unroll
    for (int r = 0; r < 4; r++) {
      int row = quad * 4 + r;
      myP[row * 40 + l15] = (bf16_t)p0[r];
      myP[row * 40 + 16 + l15] = (bf16_t)p1[r];
    }
    asm volatile("s_waitcnt lgkmcnt(0)" ::: "memory");
    // A-layout read: m=l15, k=quad*8..+8
    bf16x8 pf = *(const bf16x8*)(myP + l15 * 40 + quad * 8);
    const bf16_t* vp = VtH + (size_t)l15 * SEQ + kt0 + quad * 8;
#pragma unroll
    for (int dt = 0; dt < 8; dt++) {
      bf16x8 vf = *(const bf16x8*)(vp + (size_t)dt * 16 * SEQ);
      acc[dt] = mfma16(pf, vf, acc[dt]);
    }
  }
  float inv[4];
#pragma unroll
  for (int r = 0; r < 4; r++) inv[r] = 1.0f / lrow[r];
#pragma unroll
  for (int dt = 0; dt < 8; dt++)
#pragma unroll
    for (int r = 0; r < 4; r++) {
      int trow = qbase + w * 16 + quad * 4 + r;
      AO[(size_t)trow * DIM + h * HD + dt * 16 + l15] = (bf16_t)(acc[dt][r] * inv[r]);
    }
}

extern "C" void kernel_launch(void* const* d_in, const int* in_sizes, int n_in,
                              void* d_out, int out_size, void* d_ws, size_t ws_size,
                              hipStream_t stream) {
  const float* x = (const float*)d_in[0];
  const float* wq = (const float*)d_in[1];
  const float* wk = (const float*)d_in[2];
  const float* wv = (const float*)d_in[3];
  const float* wo = (const float*)d_in[4];
  float* out = (float*)d_out;
  float* kOut = out + (size_t)SEQ * DIM;             // (32,2048,128)
  float* vOut = kOut + (size_t)NH * SEQ * HD;        // (32,2048,128)

  // workspace layout (total 142,606,336 B):
  char* ws = (char*)d_ws;
  bf16_t* Xb = (bf16_t*)ws;                          // 16 MB; later aliased as AO
  bf16_t* WT = (bf16_t*)(ws + 16777216);             // 48 MB: [wq^T|wk^T|wv^T] (6144 x 4096)
  float* QKV = (float*)(ws + 67108864);              // 48 MB fp32 (2048 x 6144)
  bf16_t* WoT = (bf16_t*)(ws + 67108864);            // alias of QKV (QKV dead by then)
  bf16_t* Qb = (bf16_t*)(ws + 117440512);            // 16 MB
  bf16_t* Kb = (bf16_t*)(ws + 134217728);            // 4 MB
  bf16_t* Vt = (bf16_t*)(ws + 138412032);            // 4 MB
  bf16_t* AO = Xb;                                   // attention output bf16 (2048 x 4096)

  dim3 tb(32, 8);
  cast_x<<<8192, 256, 0, stream>>>(x, Xb);
  tcast<<<dim3(128, 128), tb, 0, stream>>>(wq, WT, 4096, 4096);
  tcast<<<dim3(32, 128), tb, 0, stream>>>(wk, WT + (size_t)4096 * 4096, 1024, 4096);
  tcast<<<dim3(32, 128), tb, 0, stream>>>(wv, WT + (size_t)5120 * 4096, 1024, 4096);
  gemm_bt<<<dim3(48, 16), 256, 0, stream>>>(Xb, WT, QKV, 2048, 6144, 4096);
  rope_scatter<<<24576, 256, 0, stream>>>(QKV, Qb, Kb, Vt, kOut, vOut);
  tcast<<<dim3(128, 128), tb, 0, stream>>>(wo, WoT, 4096, 4096);
  attn_kernel<<<dim3(32, 32), 256, 0, stream>>>(Qb, Kb, Vt, AO);
  gemm_bt<<<dim3(32, 16), 256, 0, stream>>>(AO, WoT, out, 2048, 4096, 4096);
}

// Round 3
// 594.121 us; speedup vs baseline: 1.6143x; 1.6143x over previous
//
#include <hip/hip_runtime.h>
#include <cstdint>
#include <cstddef>

#define DIM 4096
#define SEQ 2048
#define NH 32
#define NKV 8
#define HD 128
#define QKVN 6144

typedef __bf16 bf16_t;
typedef __bf16 bf16x8 __attribute__((ext_vector_type(8)));
typedef __bf16 bf16x4 __attribute__((ext_vector_type(4)));
typedef __bf16 bf16x2 __attribute__((ext_vector_type(2)));
typedef float f32x4 __attribute__((ext_vector_type(4)));
typedef int int4v __attribute__((ext_vector_type(4)));

__device__ __forceinline__ f32x4 mfma16(bf16x8 a, bf16x8 b, f32x4 c) {
  return __builtin_amdgcn_mfma_f32_16x16x32_bf16(a, b, c, 0, 0, 0);
}

__device__ __forceinline__ void async16(const bf16_t* g, bf16_t* l) {
  __builtin_amdgcn_global_load_lds((__attribute__((address_space(1))) void*)g,
                                   (__attribute__((address_space(3))) void*)l,
                                   16, 0, 0);
}

__device__ __forceinline__ int pack2(float a, float b) {
  bf16x2 h = { (bf16_t)a, (bf16_t)b };
  return __builtin_bit_cast(int, h);
}

// ---------------- cast x (fp32 -> bf16), 4 elems/thread ----------------
__global__ void cast_x(const float* __restrict__ x, bf16_t* __restrict__ xb) {
  int i = blockIdx.x * 256 + threadIdx.x;
  const float4 v = ((const float4*)x)[i];
  bf16x4 o = { (bf16_t)v.x, (bf16_t)v.y, (bf16_t)v.z, (bf16_t)v.w };
  *(bf16x4*)(xb + (size_t)i * 4) = o;
}

// ------- transpose-cast: src fp32 (Kdim x Ncols) -> dst bf16 (Ncols x Kdim) -------
__global__ void tcast(const float* __restrict__ src, bf16_t* __restrict__ dst,
                      int Ncols, int Kdim) {
  __shared__ float tile[32][33];
  int n0 = blockIdx.x * 32, k0 = blockIdx.y * 32;
  int tx = threadIdx.x, ty = threadIdx.y;  // 32 x 8
#pragma unroll
  for (int r = 0; r < 4; r++)
    tile[ty + 8 * r][tx] = src[(size_t)(k0 + ty + 8 * r) * Ncols + n0 + tx];
  __syncthreads();
#pragma unroll
  for (int r = 0; r < 4; r++)
    dst[(size_t)(n0 + ty + 8 * r) * Kdim + k0 + tx] = (bf16_t)tile[tx][ty + 8 * r];
}

// ---------------- GEMM: C(MxN) fp32 = A(MxK) bf16 @ Bt(NxK)^T ----------------
__global__ __launch_bounds__(256) void gemm_bt(const bf16_t* __restrict__ A,
                                               const bf16_t* __restrict__ Bt,
                                               float* __restrict__ C,
                                               int M, int N, int K) {
  __shared__ bf16_t As[128 * 32];
  __shared__ bf16_t Bs[128 * 32];
  const int t = threadIdx.x;
  const int bm = blockIdx.y * 128, bn = blockIdx.x * 128;
  const int lane = t & 63, l15 = lane & 15, quad = lane >> 4;
  const int w = t >> 6;
  const int wm = (w & 1) * 64, wn = (w >> 1) * 64;
  f32x4 acc[4][4] = {};
  const bf16_t* gA = A + (size_t)(bm + (t >> 2)) * K + (t & 3) * 8;
  const bf16_t* gB = Bt + (size_t)(bn + (t >> 2)) * K + (t & 3) * 8;
  bf16_t* lA = As + t * 8;
  bf16_t* lB = Bs + t * 8;
  for (int k0 = 0; k0 < K; k0 += 32) {
    async16(gA + k0, lA);
    async16(gA + k0 + (size_t)64 * K, lA + 2048);
    async16(gB + k0, lB);
    async16(gB + k0 + (size_t)64 * K, lB + 2048);
    __syncthreads();
    bf16x8 af[4], bfr[4];
#pragma unroll
    for (int mi = 0; mi < 4; mi++)
      af[mi] = *(const bf16x8*)(As + (wm + mi * 16 + l15) * 32 + quad * 8);
#pragma unroll
    for (int ni = 0; ni < 4; ni++)
      bfr[ni] = *(const bf16x8*)(Bs + (wn + ni * 16 + l15) * 32 + quad * 8);
#pragma unroll
    for (int mi = 0; mi < 4; mi++)
#pragma unroll
      for (int ni = 0; ni < 4; ni++)
        acc[mi][ni] = mfma16(af[mi], bfr[ni], acc[mi][ni]);
    __syncthreads();
  }
#pragma unroll
  for (int mi = 0; mi < 4; mi++)
#pragma unroll
    for (int ni = 0; ni < 4; ni++) {
      size_t row = (size_t)bm + wm + mi * 16 + quad * 4;
      size_t col = (size_t)bn + wn + ni * 16 + l15;
#pragma unroll
      for (int r = 0; r < 4; r++)
        C[(row + r) * N + col] = acc[mi][ni][r];
    }
}

// ---------------- RoPE + scatter ----------------
// Q outputs pre-scaled by SCALE*log2(e) so attention uses exp2 directly.
// Vt is written with keys PERMUTED within each 32-key chunk:
//   slot s = ((t&12)<<1) + (t&3) + ((t&16)>>2)   (t = key mod 32)
// matching the PV B-fragment identity layout in attn_kernel.
__global__ void rope_scatter(const float* __restrict__ qkv, bf16_t* __restrict__ Qb,
                             bf16_t* __restrict__ Kb, bf16_t* __restrict__ Vt,
                             float* __restrict__ kOut, float* __restrict__ vOut) {
  int idx = blockIdx.x * 256 + threadIdx.x;
  int t = idx / 3072;
  int p = idx - t * 3072;
  const float NEG_L2T_64 = -0.20762050593046f;  // -log2(10000)/64
  const float SS = 0.08838834764831845f * 1.4426950408889634f;  // SCALE*log2(e)
  if (p < 2048) {  // Q
    int hh = p >> 6, pr = p & 63;
    int d0 = pr << 1;
    const float* src = qkv + (size_t)t * QKVN + hh * HD + d0;
    float a = src[0], b = src[1];
    int j0 = d0 & 63, j1 = (d0 + 1) & 63;
    float th0 = (float)t * exp2f((float)j0 * NEG_L2T_64);
    float th1 = (float)t * exp2f((float)j1 * NEG_L2T_64);
    float o0 = (a * cosf(th0) - b * sinf(th0)) * SS;
    float o1 = (b * cosf(th1) + a * sinf(th1)) * SS;
    bf16_t* dst = Qb + ((size_t)hh * SEQ + t) * HD + d0;
    dst[0] = (bf16_t)o0;
    dst[1] = (bf16_t)o1;
  } else if (p < 2560) {  // K
    int q2 = p - 2048;
    int kh = q2 >> 6, pr = q2 & 63;
    int d0 = pr << 1;
    const float* src = qkv + (size_t)t * QKVN + 4096 + kh * HD + d0;
    float a = src[0], b = src[1];
    int j0 = d0 & 63, j1 = (d0 + 1) & 63;
    float th0 = (float)t * exp2f((float)j0 * NEG_L2T_64);
    float th1 = (float)t * exp2f((float)j1 * NEG_L2T_64);
    float o0 = a * cosf(th0) - b * sinf(th0);
    float o1 = b * cosf(th1) + a * sinf(th1);
    bf16_t* dst = Kb + ((size_t)kh * SEQ + t) * HD + d0;
    dst[0] = (bf16_t)o0;
    dst[1] = (bf16_t)o1;
#pragma unroll
    for (int rep = 0; rep < 4; rep++) {
      float* kp = kOut + ((size_t)(kh * 4 + rep) * SEQ + t) * HD + d0;
      kp[0] = o0;
      kp[1] = o1;
    }
  } else {  // V
    int q2 = p - 2560;
    int kh = q2 >> 6, pr = q2 & 63;
    int d0 = pr << 1;
    const float* src = qkv + (size_t)t * QKVN + 5120 + kh * HD + d0;
    float a = src[0], b = src[1];
#pragma unroll
    for (int rep = 0; rep < 4; rep++) {
      float* vp = vOut + ((size_t)(kh * 4 + rep) * SEQ + t) * HD + d0;
      vp[0] = a;
      vp[1] = b;
    }
    // permuted key position for attention's PV slot ordering
    int tp = (t & ~31) + ((t & 12) << 1) + (t & 3) + ((t & 16) >> 2);
    Vt[((size_t)kh * HD + d0) * SEQ + tp] = (bf16_t)a;
    Vt[((size_t)kh * HD + d0 + 1) * SEQ + tp] = (bf16_t)b;
  }
}

// ---------------- Flash attention ----------------
// Grid: (8 q-tiles of 256 rows, 32 heads). 512 threads = 8 waves x 32 q-rows.
// S^T = K*Qs^T; fixed-max exp2 softmax; K/V (KT=64) double-buffered via
// global_load_lds. PV B-fragment is built IDENTITY from the lane's own S
// registers (slot order quad*8+j <-> lo/hi S-tile rows quad*4..); V was
// pre-permuted in rope_scatter to match.
__global__ __launch_bounds__(512, 2) void attn_kernel(const bf16_t* __restrict__ Qb,
                                                      const bf16_t* __restrict__ Kb,
                                                      const bf16_t* __restrict__ Vt,
                                                      bf16_t* __restrict__ AO) {
  __shared__ bf16_t Ks[2][8192];  // [buf][kc(4)][key(64)][d(32)]
  __shared__ bf16_t Vs[2][8192];  // [buf][kt(2)][d(128)][slot(32)]
  const int h = blockIdx.y, kh = h >> 2;
  const int qbase = blockIdx.x * 256;
  const int w = threadIdx.x >> 6, lane = threadIdx.x & 63;
  const int l15 = lane & 15, quad = lane >> 4;
  const bf16_t* KbH = Kb + (size_t)kh * SEQ * HD;
  const bf16_t* VtH = Vt + (size_t)kh * HD * SEQ;

  // persistent Q fragments: this wave's 32 q-rows (B-operand: n=q, k=d)
  bf16x8 qf[2][4];
#pragma unroll
  for (int nq = 0; nq < 2; nq++) {
    const bf16_t* qp = Qb + ((size_t)h * SEQ + qbase + w * 32 + nq * 16 + l15) * HD + quad * 8;
#pragma unroll
    for (int kc = 0; kc < 4; kc++) qf[nq][kc] = *(const bf16x8*)(qp + kc * 32);
  }

  f32x4 acc[8][2] = {};       // O^T: [d-tile][q-tile], d=quad*4+r, q=l15
  float rsum[2] = {0.f, 0.f};

  auto stage = [&](int buf, int kt0) {
    if (w < 4) {  // K tile: waves 0-3, one 32-d chunk each
      int kc = w;
#pragma unroll
      for (int kg = 0; kg < 4; kg++) {
        const bf16_t* g = KbH + (size_t)(kt0 + kg * 16 + (lane >> 2)) * HD + kc * 32 + (lane & 3) * 8;
        async16(g, &Ks[buf][kc * 2048 + kg * 512]);
      }
    } else {  // V tile: waves 4-7
      int vi = w - 4, kt = vi >> 1, dg0 = (vi & 1) * 4;
#pragma unroll
      for (int j = 0; j < 4; j++) {
        int dg = dg0 + j;
        const bf16_t* g = VtH + (size_t)(dg * 16 + (lane >> 2)) * SEQ + kt0 + kt * 32 + (lane & 3) * 8;
        async16(g, &Vs[buf][kt * 4096 + dg * 512]);
      }
    }
  };

  stage(0, 0);
  int buf = 0;

  for (int kt0 = 0; kt0 < SEQ; kt0 += 64, buf ^= 1) {
    __syncthreads();  // drains this wave's staging vmcnt; buf ready
    if (kt0 + 64 < SEQ) stage(buf ^ 1, kt0 + 64);

    // S^T = K * Qs^T  (A = K rows: m=key, k=d; B = Q rows: n=q, k=d)
    f32x4 sacc[4][2] = {};
#pragma unroll
    for (int mi = 0; mi < 4; mi++)
#pragma unroll
      for (int kc = 0; kc < 4; kc++) {
        bf16x8 kf = *(const bf16x8*)(&Ks[buf][(kc * 64 + mi * 16 + l15) * 32 + quad * 8]);
#pragma unroll
        for (int nq = 0; nq < 2; nq++)
          sacc[mi][nq] = mfma16(kf, qf[nq][kc], sacc[mi][nq]);
      }

    // p = exp2(s) (fixed max), per-lane partial row sums, pack to bf16 pairs
    int pk[4][2][2];
#pragma unroll
    for (int mi = 0; mi < 4; mi++)
#pragma unroll
      for (int nq = 0; nq < 2; nq++) {
        float p0 = exp2f(sacc[mi][nq][0]);
        float p1 = exp2f(sacc[mi][nq][1]);
        float p2 = exp2f(sacc[mi][nq][2]);
        float p3 = exp2f(sacc[mi][nq][3]);
        rsum[nq] += (p0 + p1) + (p2 + p3);
        pk[mi][nq][0] = pack2(p0, p1);
        pk[mi][nq][1] = pack2(p2, p3);
      }

    // PV: O^T += V_perm * P_slots. B-frag = lane's own registers (identity):
    // slot quad*8+j: j0..3 -> lo tile (mi=2kt) rows quad*4+j, j4..7 -> hi tile.
#pragma unroll
    for (int kt = 0; kt < 2; kt++) {
#pragma unroll
      for (int nq = 0; nq < 2; nq++) {
        int4v dw;
        dw[0] = pk[2 * kt][nq][0];
        dw[1] = pk[2 * kt][nq][1];
        dw[2] = pk[2 * kt + 1][nq][0];
        dw[3] = pk[2 * kt + 1][nq][1];
        bf16x8 pf = __builtin_bit_cast(bf16x8, dw);
#pragma unroll
        for (int dt = 0; dt < 8; dt++) {
          bf16x8 vf = *(const bf16x8*)(&Vs[buf][(kt * 128 + dt * 16 + l15) * 32 + quad * 8]);
          acc[dt][nq] = mfma16(vf, pf, acc[dt][nq]);
        }
      }
    }
  }

  // epilogue: finish row sums (reduce across quad lanes), normalize, store O
#pragma unroll
  for (int nq = 0; nq < 2; nq++) {
    float rs = rsum[nq];
    rs += __shfl_xor(rs, 16);
    rs += __shfl_xor(rs, 32);
    float inv = 1.0f / rs;
    int q = qbase + w * 32 + nq * 16 + l15;
#pragma unroll
    for (int dt = 0; dt < 8; dt++) {
      bf16x4 o = { (bf16_t)(acc[dt][nq][0] * inv), (bf16_t)(acc[dt][nq][1] * inv),
                   (bf16_t)(acc[dt][nq][2] * inv), (bf16_t)(acc[dt][nq][3] * inv) };
      *(bf16x4*)(AO + (size_t)q * DIM + h * HD + dt * 16 + quad * 4) = o;
    }
  }
}

extern "C" void kernel_launch(void* const* d_in, const int* in_sizes, int n_in,
                              void* d_out, int out_size, void* d_ws, size_t ws_size,
                              hipStream_t stream) {
  const float* x = (const float*)d_in[0];
  const float* wq = (const float*)d_in[1];
  const float* wk = (const float*)d_in[2];
  const float* wv = (const float*)d_in[3];
  const float* wo = (const float*)d_in[4];
  float* out = (float*)d_out;
  float* kOut = out + (size_t)SEQ * DIM;
  float* vOut = kOut + (size_t)NH * SEQ * HD;

  char* ws = (char*)d_ws;
  bf16_t* Xb = (bf16_t*)ws;                          // 16 MB; later aliased as AO
  bf16_t* WT = (bf16_t*)(ws + 16777216);             // 48 MB: [wq^T|wk^T|wv^T]
  float* QKV = (float*)(ws + 67108864);              // 48 MB fp32
  bf16_t* WoT = (bf16_t*)(ws + 67108864);            // alias (QKV dead by then)
  bf16_t* Qb = (bf16_t*)(ws + 117440512);            // 16 MB
  bf16_t* Kb = (bf16_t*)(ws + 134217728);            // 4 MB
  bf16_t* Vt = (bf16_t*)(ws + 138412032);            // 4 MB (slot-permuted keys)
  bf16_t* AO = Xb;

  dim3 tb(32, 8);
  cast_x<<<8192, 256, 0, stream>>>(x, Xb);
  tcast<<<dim3(128, 128), tb, 0, stream>>>(wq, WT, 4096, 4096);
  tcast<<<dim3(32, 128), tb, 0, stream>>>(wk, WT + (size_t)4096 * 4096, 1024, 4096);
  tcast<<<dim3(32, 128), tb, 0, stream>>>(wv, WT + (size_t)5120 * 4096, 1024, 4096);
  gemm_bt<<<dim3(48, 16), 256, 0, stream>>>(Xb, WT, QKV, 2048, 6144, 4096);
  rope_scatter<<<24576, 256, 0, stream>>>(QKV, Qb, Kb, Vt, kOut, vOut);
  tcast<<<dim3(128, 128), tb, 0, stream>>>(wo, WoT, 4096, 4096);
  attn_kernel<<<dim3(8, 32), 512, 0, stream>>>(Qb, Kb, Vt, AO);
  gemm_bt<<<dim3(32, 16), 256, 0, stream>>>(AO, WoT, out, 2048, 4096, 4096);
}